// Round 4
// baseline (99.375 us; speedup 1.0000x reference)
//
#include <hip/hip_runtime.h>
#include <hip/hip_bf16.h>

// Deformable conv2d (v1, align_corners=True, zeros padding), NHWC-bf16 + MFMA.
// R13 = R12 + two micro-opts in main (values bit-identical to R12):
//  - packed blend: bilinear blend rewritten as f32x2 ext-vector ops with
//    __builtin_elementwise_fma -> v_pk_mul_f32/v_pk_fma_f32 (VOP3P), cutting
//    the per-(cc,k) blend from 17 to 13 VALU inst (~-19% of main's VALU).
//    pk-fma == two scalar fmas -> numerics unchanged.
//  - gather x2: tile gather remapped 240x(64 scalar loads) -> 120 threads x
//    2 adjacent pixels x (64 float2 loads): same bytes, half the VMEM
//    instructions. Same swizzled b128 LDS writes (pixel pairs stay in-row,
//    24 even; slot parity alternates sw0/sw0+1).
// x(4,64,128,128) f32, offset(4,18,128,128) f32, weight(64,64,9) f32
// -> out(4,64,128,128) f32.  iy = oh + off_y, ix = ow + off_x.

#define NB 4
#define CI 64
#define HH 128
#define WW 128
#define OCH 64
#define KNN 9
#define HW (HH * WW)

typedef unsigned int u32;
typedef unsigned short u16;
typedef __attribute__((ext_vector_type(8))) short bf16x8;
typedef __attribute__((ext_vector_type(4))) float f32x4;
typedef __attribute__((ext_vector_type(2))) float f32x2;

__device__ inline u16 f2bf(float f) {  // RNE
    u32 u = __float_as_uint(f);
    return (u16)((u + 0x7fffu + ((u >> 16) & 1u)) >> 16);
}
__device__ inline u32 pk2(float lo, float hi) {
    return (u32)f2bf(lo) | ((u32)f2bf(hi) << 16);
}
__device__ inline f32x2 up2p(u32 u) {
    f32x2 r;
    r.x = __uint_as_float(u << 16);
    r.y = __uint_as_float(u & 0xffff0000u);
    return r;
}
__device__ inline u32 pkrn2(f32x2 s) {
    union { __hip_bfloat162 b; u32 u; } c;
    c.b = __float22bfloat162_rn(float2{s.x, s.y});
    return c.u;
}

// ---- tiny prologue: weight -> A-fragment order bf16.
// wf layout: frag[kn][chunk(2)][strip(4)][lane(64)][j(8)]; lane holds
// A[m=lane&15][k=(lane>>4)*8+j], oc = strip*16+m, c = chunk*32+k.
__global__ __launch_bounds__(256) void wf_prep_kernel(const float* __restrict__ w,
                                                      u16* __restrict__ wf) {
    int i = blockIdx.x * 256 + threadIdx.x;
    if (i < KNN * 2 * 4 * 64 * 8) {
        int j = i & 7, l = (i >> 3) & 63, strip = (i >> 9) & 3,
            chunk = (i >> 11) & 1, kn = i >> 12;
        int oc = strip * 16 + (l & 15);
        int c = chunk * 32 + ((l >> 4) & 3) * 8 + j;
        wf[i] = f2bf(w[(oc * CI + c) * KNN + kn]);
    }
}

// ---- main kernel: block = 16x4 patch (4 row-waves), 64 oc, fused-transpose
// LDS input tile gathered straight from f32 NCHW.
__global__ __launch_bounds__(256, 4) void dcn_main_kernel(const float* __restrict__ x,
                                                          const float* __restrict__ off,
                                                          const u16* __restrict__ wf,
                                                          float* __restrict__ out) {
    // 10x24 pixels x 64ch bf16; pixel row = 32 dw (128B); chunk q at q^(P&7).
    __shared__ __align__(16) u32 tile[240 * 32];  // 30,720 B
    const int tid = threadIdx.x;
    const int l = tid & 63;
    const int wv = tid >> 6;

    // XCD-affine decode: xcd = blockIdx&7; n = xcd>>1; half = xcd&1.
    const int b = blockIdx.x;
    const int xcd = b & 7;
    const int n = xcd >> 1;
    const int patch = (b >> 3) + ((xcd & 1) << 7);  // 0..255
    const int py = (patch >> 3) << 2;   // patch row (0..31) * 4
    const int px = (patch & 7) << 4;    // patch col (0..7) * 16
    const int ty = min(max(py - 3, 0), HH - 10);
    const int tx = min(max(px - 4, 0), WW - 24);

    const float* xN = x + ((size_t)n << 20);          // n * 64 * 16384 floats
    const float* offn = off + n * (2 * KNN * HW);

    // cooperative fused-transpose tile load: threads 0..119 each own TWO
    // adjacent pixels (p0, p0+1); per 16B chunk q: 8 float2 NCHW loads
    // (each covers both pixels of one channel), pack to bf16, two swizzled
    // b128 writes at slots q^(P&7).  Bit-identical tile values to R12.
    if (tid < 120) {
        const int p0 = tid << 1;
        const int tr = (p0 * 171) >> 12;  // p0 / 24 for p0 < 240
        const int tc = p0 - tr * 24;      // even, <= 22: pair stays in-row
        const float* src = xN + ((ty + tr) << 7) + (tx + tc);
        u32* dst0 = &tile[p0 << 5];
        u32* dst1 = &tile[(p0 + 1) << 5];
        const int sw0 = p0 & 7;          // even
        const int sw1 = sw0 + 1;
#pragma unroll
        for (int q = 0; q < 8; q++) {
            float2 a0 = *(const float2*)&src[(q * 8 + 0) * HW];
            float2 a1 = *(const float2*)&src[(q * 8 + 1) * HW];
            float2 a2 = *(const float2*)&src[(q * 8 + 2) * HW];
            float2 a3 = *(const float2*)&src[(q * 8 + 3) * HW];
            float2 a4 = *(const float2*)&src[(q * 8 + 4) * HW];
            float2 a5 = *(const float2*)&src[(q * 8 + 5) * HW];
            float2 a6 = *(const float2*)&src[(q * 8 + 6) * HW];
            float2 a7 = *(const float2*)&src[(q * 8 + 7) * HW];
            *(uint4*)&dst0[(q ^ sw0) << 2] = make_uint4(
                pk2(a0.x, a1.x), pk2(a2.x, a3.x), pk2(a4.x, a5.x), pk2(a6.x, a7.x));
            *(uint4*)&dst1[(q ^ sw1) << 2] = make_uint4(
                pk2(a0.y, a1.y), pk2(a2.y, a3.y), pk2(a4.y, a5.y), pk2(a6.y, a7.y));
        }
    }

    const int col = l & 15;
    const int oh = py + wv;         // one output row per wave
    const int ow = px + col;        // 16 consecutive columns
    const int rr = (oh << 7) + ow;
    const int qc = l >> 4;          // channel chunk index 0..3 (16B chunks)
    const int cb = qc << 3;         // channel base (channels / halfwords)

    // preload all 18 offsets (overlaps the tile gather); 1 x 64B line each
    float offy[KNN], offx[KNN];
#pragma unroll
    for (int kn = 0; kn < KNN; kn++) {
        offy[kn] = offn[(2 * kn) * HW + rr];
        offx[kn] = offn[(2 * kn + 1) * HW + rr];
    }

    __syncthreads();  // tile resident

    const bf16x8* wfv = (const bf16x8*)wf;
    f32x4 acc[4] = {{0, 0, 0, 0}, {0, 0, 0, 0}, {0, 0, 0, 0}, {0, 0, 0, 0}};

#pragma unroll
    for (int kn = 0; kn < KNN; kn++) {
        float iy = (float)oh + offy[kn], ix = (float)ow + offx[kn];
        float y0f = floorf(iy), x0f = floorf(ix);
        float wy1 = iy - y0f, wy0 = 1.f - wy1;
        float wx1 = ix - x0f, wx0 = 1.f - wx1;
        float my0 = (y0f >= 0.f && y0f <= 127.f) ? 1.f : 0.f;
        float my1 = (y0f >= -1.f && y0f <= 126.f) ? 1.f : 0.f;
        float mx0 = (x0f >= 0.f && x0f <= 127.f) ? 1.f : 0.f;
        float mx1 = (x0f >= -1.f && x0f <= 126.f) ? 1.f : 0.f;
        float W0 = wy0 * wx0 * my0 * mx0, W1 = wy0 * wx1 * my0 * mx1;
        float W2 = wy1 * wx0 * my1 * mx0, W3 = wy1 * wx1 * my1 * mx1;
        const f32x2 W0p = {W0, W0}, W1p = {W1, W1}, W2p = {W2, W2}, W3p = {W3, W3};
        int y0 = min(max((int)y0f, 0), 127), y1 = min(max((int)y0f + 1, 0), 127);
        int x0 = min(max((int)x0f, 0), 127), x1 = min(max((int)x0f + 1, 0), 127);

        // tile-local coords (clamped for LDS safety; oot lanes overwritten)
        const int dy0 = min(max(y0 - ty, 0), 9), dy1 = min(max(y1 - ty, 0), 9);
        const int dx0 = min(max(x0 - tx, 0), 23), dx1 = min(max(x1 - tx, 0), 23);
        const int P0 = dy0 * 24 + dx0, P1 = dy0 * 24 + dx1;
        const int P2 = dy1 * 24 + dx0, P3 = dy1 * 24 + dx1;
        const bool oot = (y0 < ty) | (y1 > ty + 9) | (x0 < tx) | (x1 > tx + 23);

        // 8 ds_read_b128: 4 corners x 2 channel-chunks (q = qc, qc+4), swizzled
        uint4 Q0a = *(const uint4*)&tile[(P0 << 5) + (((qc    ) ^ (P0 & 7)) << 2)];
        uint4 Q0b = *(const uint4*)&tile[(P0 << 5) + (((qc + 4) ^ (P0 & 7)) << 2)];
        uint4 Q1a = *(const uint4*)&tile[(P1 << 5) + (((qc    ) ^ (P1 & 7)) << 2)];
        uint4 Q1b = *(const uint4*)&tile[(P1 << 5) + (((qc + 4) ^ (P1 & 7)) << 2)];
        uint4 Q2a = *(const uint4*)&tile[(P2 << 5) + (((qc    ) ^ (P2 & 7)) << 2)];
        uint4 Q2b = *(const uint4*)&tile[(P2 << 5) + (((qc + 4) ^ (P2 & 7)) << 2)];
        uint4 Q3a = *(const uint4*)&tile[(P3 << 5) + (((qc    ) ^ (P3 & 7)) << 2)];
        uint4 Q3b = *(const uint4*)&tile[(P3 << 5) + (((qc + 4) ^ (P3 & 7)) << 2)];
        if (oot) {  // rare (~0.3% of lane-kn): exact NCHW gather fallback
            const int O0 = (y0 << 7) + x0, O1 = (y0 << 7) + x1;
            const int O2 = (y1 << 7) + x0, O3 = (y1 << 7) + x1;
            const float* p;
            p = xN + O0 + cb * HW;
            Q0a = make_uint4(pk2(p[0], p[HW]), pk2(p[2 * HW], p[3 * HW]),
                             pk2(p[4 * HW], p[5 * HW]), pk2(p[6 * HW], p[7 * HW]));
            p += 32 * HW;
            Q0b = make_uint4(pk2(p[0], p[HW]), pk2(p[2 * HW], p[3 * HW]),
                             pk2(p[4 * HW], p[5 * HW]), pk2(p[6 * HW], p[7 * HW]));
            p = xN + O1 + cb * HW;
            Q1a = make_uint4(pk2(p[0], p[HW]), pk2(p[2 * HW], p[3 * HW]),
                             pk2(p[4 * HW], p[5 * HW]), pk2(p[6 * HW], p[7 * HW]));
            p += 32 * HW;
            Q1b = make_uint4(pk2(p[0], p[HW]), pk2(p[2 * HW], p[3 * HW]),
                             pk2(p[4 * HW], p[5 * HW]), pk2(p[6 * HW], p[7 * HW]));
            p = xN + O2 + cb * HW;
            Q2a = make_uint4(pk2(p[0], p[HW]), pk2(p[2 * HW], p[3 * HW]),
                             pk2(p[4 * HW], p[5 * HW]), pk2(p[6 * HW], p[7 * HW]));
            p += 32 * HW;
            Q2b = make_uint4(pk2(p[0], p[HW]), pk2(p[2 * HW], p[3 * HW]),
                             pk2(p[4 * HW], p[5 * HW]), pk2(p[6 * HW], p[7 * HW]));
            p = xN + O3 + cb * HW;
            Q3a = make_uint4(pk2(p[0], p[HW]), pk2(p[2 * HW], p[3 * HW]),
                             pk2(p[4 * HW], p[5 * HW]), pk2(p[6 * HW], p[7 * HW]));
            p += 32 * HW;
            Q3b = make_uint4(pk2(p[0], p[HW]), pk2(p[2 * HW], p[3 * HW]),
                             pk2(p[4 * HW], p[5 * HW]), pk2(p[6 * HW], p[7 * HW]));
        }

#pragma unroll
        for (int cc = 0; cc < 2; cc++) {
            const u32* c0 = (const u32*)(cc ? &Q0b : &Q0a);
            const u32* c1 = (const u32*)(cc ? &Q1b : &Q1a);
            const u32* c2 = (const u32*)(cc ? &Q2b : &Q2a);
            const u32* c3 = (const u32*)(cc ? &Q3b : &Q3a);
            union { u32 u[4]; bf16x8 v; } B;
#pragma unroll
            for (int k = 0; k < 4; k++) {
                f32x2 s = up2p(c0[k]) * W0p;  // v_pk_mul_f32
                s = __builtin_elementwise_fma(up2p(c1[k]), W1p, s);
                s = __builtin_elementwise_fma(up2p(c2[k]), W2p, s);
                s = __builtin_elementwise_fma(up2p(c3[k]), W3p, s);
                B.u[k] = pkrn2(s);
            }
#pragma unroll
            for (int s4 = 0; s4 < 4; s4++) {
                bf16x8 A = wfv[((((kn << 1) + cc) << 2) + s4) * 64 + l];
                acc[s4] = __builtin_amdgcn_mfma_f32_16x16x32_bf16(A, B.v, acc[s4], 0, 0, 0);
            }
        }
    }

    // epilogue: D layout col(pixel)=l&15, row(oc-in-strip)=(l>>4)*4+reg.
    // lanes 0..15 -> 16 consecutive ow: each store instr = 4 dense 64B lines.
    const int rq = l >> 4;
    float* op = out + ((size_t)(n * OCH) << 14);
#pragma unroll
    for (int s = 0; s < 4; s++) {
        const int ocb = (s << 4) + (rq << 2);
#pragma unroll
        for (int g = 0; g < 4; g++) {
            op[((ocb + g) << 14) + rr] = acc[s][g];
        }
    }
}

// ---- fallback (ws too small): round-1 style direct kernel
__global__ __launch_bounds__(256) void dcn_fallback_kernel(
    const float* __restrict__ x, const float* __restrict__ off,
    const float* __restrict__ w, float* __restrict__ out) {
    int p = blockIdx.x * blockDim.x + threadIdx.x;
    int n = p / HW, r = p % HW, oh = r / WW, ow = r % WW;
    float acc[OCH];
#pragma unroll
    for (int i = 0; i < OCH; i++) acc[i] = 0.f;
    const float* xn = x + n * (CI * HW);
    const float* offn = off + n * (2 * KNN * HW);
    for (int kn = 0; kn < KNN; kn++) {
        float iy = (float)oh + offn[(2 * kn) * HW + r];
        float ix = (float)ow + offn[(2 * kn + 1) * HW + r];
        float y0f = floorf(iy), x0f = floorf(ix);
        float wy1 = iy - y0f, wy0 = 1.f - wy1, wx1 = ix - x0f, wx0 = 1.f - wx1;
        float my0 = (y0f >= 0.f && y0f <= 127.f) ? 1.f : 0.f;
        float my1 = (y0f >= -1.f && y0f <= 126.f) ? 1.f : 0.f;
        float mx0 = (x0f >= 0.f && x0f <= 127.f) ? 1.f : 0.f;
        float mx1 = (x0f >= -1.f && x0f <= 126.f) ? 1.f : 0.f;
        float w00 = wy0 * wx0 * my0 * mx0, w01 = wy0 * wx1 * my0 * mx1;
        float w10 = wy1 * wx0 * my1 * mx0, w11 = wy1 * wx1 * my1 * mx1;
        int y0 = min(max((int)y0f, 0), 127), y1 = min(max((int)y0f + 1, 0), 127);
        int x0 = min(max((int)x0f, 0), 127), x1 = min(max((int)x0f + 1, 0), 127);
        int o00 = y0 * WW + x0, o01 = y0 * WW + x1, o10 = y1 * WW + x0, o11 = y1 * WW + x1;
        for (int c = 0; c < CI; c++) {
            const float* xc = xn + c * HW;
            float s = xc[o00] * w00 + xc[o01] * w01 + xc[o10] * w10 + xc[o11] * w11;
#pragma unroll
            for (int oc = 0; oc < OCH; oc++) acc[oc] += w[(oc * CI + c) * KNN + kn] * s;
        }
    }
    float* outp = out + n * (OCH * HW) + r;
#pragma unroll
    for (int oc = 0; oc < OCH; oc++) outp[oc * HW] = acc[oc];
}

extern "C" void kernel_launch(void* const* d_in, const int* in_sizes, int n_in,
                              void* d_out, int out_size, void* d_ws, size_t ws_size,
                              hipStream_t stream) {
    const float* x = (const float*)d_in[0];
    const float* off = (const float*)d_in[1];
    const float* w = (const float*)d_in[2];
    float* out = (float*)d_out;

    const size_t wf_elems = (size_t)KNN * 2 * 4 * 64 * 8;     // 36,864 u16
    const size_t need = wf_elems * sizeof(u16);               // ~73.7 KB

    if (ws_size >= need) {
        u16* wfr = (u16*)d_ws;
        const int wf_blocks = (int)((wf_elems + 255) / 256);  // 144
        wf_prep_kernel<<<wf_blocks, 256, 0, stream>>>(w, wfr);
        dcn_main_kernel<<<NB * 256, 256, 0, stream>>>(x, off, wfr, out);
    } else {
        dcn_fallback_kernel<<<(NB * HW) / 256, 256, 0, stream>>>(x, off, w, out);
    }
}

// Round 5
// 97.067 us; speedup vs baseline: 1.0238x; 1.0238x over previous
//
#include <hip/hip_runtime.h>
#include <hip/hip_bf16.h>

// Deformable conv2d (v1, align_corners=True, zeros padding), NHWC-bf16 + MFMA.
// R14 = exact revert to R12 (best measured: 97.1us). R13's bundled micro-opts
// (f32x2 packed blend + 120-thread float2 gather) regressed +2.3us: the pk
// blend added regalloc pressure (VOP3P needs aligned pairs vs 8 live uint4s)
// and the gather remap halved load-issuing waves (MLP loss). Reverted.
//  - main gathers its 10x24x64 halo tile directly from f32 NCHW x, converts
//    to bf16 in-register, writes swizzled LDS layout (chunk q at q^(P&7)).
//  - wave geometry: 4 row-waves, each owns one 16-px output row.
//  - only the tiny wf-prep (36,864 weight frags) runs ahead of main.
// x(4,64,128,128) f32, offset(4,18,128,128) f32, weight(64,64,9) f32
// -> out(4,64,128,128) f32.  iy = oh + off_y, ix = ow + off_x.

#define NB 4
#define CI 64
#define HH 128
#define WW 128
#define OCH 64
#define KNN 9
#define HW (HH * WW)

typedef unsigned int u32;
typedef unsigned short u16;
typedef __attribute__((ext_vector_type(8))) short bf16x8;
typedef __attribute__((ext_vector_type(4))) float f32x4;

__device__ inline u16 f2bf(float f) {  // RNE
    u32 u = __float_as_uint(f);
    return (u16)((u + 0x7fffu + ((u >> 16) & 1u)) >> 16);
}
__device__ inline u32 pk2(float lo, float hi) {
    return (u32)f2bf(lo) | ((u32)f2bf(hi) << 16);
}
__device__ inline float2 up2v(u32 u) {
    return float2{__uint_as_float(u << 16), __uint_as_float(u & 0xffff0000u)};
}
__device__ inline u32 pkrn(float2 s) {
    union { __hip_bfloat162 b; u32 u; } c;
    c.b = __float22bfloat162_rn(s);
    return c.u;
}

// ---- tiny prologue: weight -> A-fragment order bf16.
// wf layout: frag[kn][chunk(2)][strip(4)][lane(64)][j(8)]; lane holds
// A[m=lane&15][k=(lane>>4)*8+j], oc = strip*16+m, c = chunk*32+k.
__global__ __launch_bounds__(256) void wf_prep_kernel(const float* __restrict__ w,
                                                      u16* __restrict__ wf) {
    int i = blockIdx.x * 256 + threadIdx.x;
    if (i < KNN * 2 * 4 * 64 * 8) {
        int j = i & 7, l = (i >> 3) & 63, strip = (i >> 9) & 3,
            chunk = (i >> 11) & 1, kn = i >> 12;
        int oc = strip * 16 + (l & 15);
        int c = chunk * 32 + ((l >> 4) & 3) * 8 + j;
        wf[i] = f2bf(w[(oc * CI + c) * KNN + kn]);
    }
}

// ---- main kernel: block = 16x4 patch (4 row-waves), 64 oc, fused-transpose
// LDS input tile gathered straight from f32 NCHW.
__global__ __launch_bounds__(256, 4) void dcn_main_kernel(const float* __restrict__ x,
                                                          const float* __restrict__ off,
                                                          const u16* __restrict__ wf,
                                                          float* __restrict__ out) {
    // 10x24 pixels x 64ch bf16; pixel row = 32 dw (128B); chunk q at q^(P&7).
    __shared__ __align__(16) u32 tile[240 * 32];  // 30,720 B
    const int tid = threadIdx.x;
    const int l = tid & 63;
    const int wv = tid >> 6;

    // XCD-affine decode: xcd = blockIdx&7; n = xcd>>1; half = xcd&1.
    const int b = blockIdx.x;
    const int xcd = b & 7;
    const int n = xcd >> 1;
    const int patch = (b >> 3) + ((xcd & 1) << 7);  // 0..255
    const int py = (patch >> 3) << 2;   // patch row (0..31) * 4
    const int px = (patch & 7) << 4;    // patch col (0..7) * 16
    const int ty = min(max(py - 3, 0), HH - 10);
    const int tx = min(max(px - 4, 0), WW - 24);

    const float* xN = x + ((size_t)n << 20);          // n * 64 * 16384 floats
    const float* offn = off + n * (2 * KNN * HW);

    // cooperative fused-transpose tile load: threads 0..239 each own one
    // pixel P=tid; per 16B chunk q: 8 strided NCHW f32 loads (lanes =
    // consecutive pixels -> 24-dword runs), pack to bf16x8, swizzled b128
    // write at slot q^(P&7).
    if (tid < 240) {
        const int tr = (tid * 171) >> 12;  // tid / 24 for tid < 240
        const int tc = tid - tr * 24;
        const float* src = xN + ((ty + tr) << 7) + (tx + tc);
        u32* dst = &tile[tid << 5];
        const int sw = tid & 7;
#pragma unroll
        for (int q = 0; q < 8; q++) {
            u32 o0 = pk2(src[(q * 8 + 0) * HW], src[(q * 8 + 1) * HW]);
            u32 o1 = pk2(src[(q * 8 + 2) * HW], src[(q * 8 + 3) * HW]);
            u32 o2 = pk2(src[(q * 8 + 4) * HW], src[(q * 8 + 5) * HW]);
            u32 o3 = pk2(src[(q * 8 + 6) * HW], src[(q * 8 + 7) * HW]);
            *(uint4*)&dst[(q ^ sw) << 2] = make_uint4(o0, o1, o2, o3);
        }
    }

    const int col = l & 15;
    const int oh = py + wv;         // one output row per wave
    const int ow = px + col;        // 16 consecutive columns
    const int rr = (oh << 7) + ow;
    const int qc = l >> 4;          // channel chunk index 0..3 (16B chunks)
    const int cb = qc << 3;         // channel base (channels / halfwords)

    // preload all 18 offsets (overlaps the tile gather); 1 x 64B line each
    float offy[KNN], offx[KNN];
#pragma unroll
    for (int kn = 0; kn < KNN; kn++) {
        offy[kn] = offn[(2 * kn) * HW + rr];
        offx[kn] = offn[(2 * kn + 1) * HW + rr];
    }

    __syncthreads();  // tile resident

    const bf16x8* wfv = (const bf16x8*)wf;
    f32x4 acc[4] = {{0, 0, 0, 0}, {0, 0, 0, 0}, {0, 0, 0, 0}, {0, 0, 0, 0}};

#pragma unroll
    for (int kn = 0; kn < KNN; kn++) {
        float iy = (float)oh + offy[kn], ix = (float)ow + offx[kn];
        float y0f = floorf(iy), x0f = floorf(ix);
        float wy1 = iy - y0f, wy0 = 1.f - wy1;
        float wx1 = ix - x0f, wx0 = 1.f - wx1;
        float my0 = (y0f >= 0.f && y0f <= 127.f) ? 1.f : 0.f;
        float my1 = (y0f >= -1.f && y0f <= 126.f) ? 1.f : 0.f;
        float mx0 = (x0f >= 0.f && x0f <= 127.f) ? 1.f : 0.f;
        float mx1 = (x0f >= -1.f && x0f <= 126.f) ? 1.f : 0.f;
        float W0 = wy0 * wx0 * my0 * mx0, W1 = wy0 * wx1 * my0 * mx1;
        float W2 = wy1 * wx0 * my1 * mx0, W3 = wy1 * wx1 * my1 * mx1;
        int y0 = min(max((int)y0f, 0), 127), y1 = min(max((int)y0f + 1, 0), 127);
        int x0 = min(max((int)x0f, 0), 127), x1 = min(max((int)x0f + 1, 0), 127);

        // tile-local coords (clamped for LDS safety; oot lanes overwritten)
        const int dy0 = min(max(y0 - ty, 0), 9), dy1 = min(max(y1 - ty, 0), 9);
        const int dx0 = min(max(x0 - tx, 0), 23), dx1 = min(max(x1 - tx, 0), 23);
        const int P0 = dy0 * 24 + dx0, P1 = dy0 * 24 + dx1;
        const int P2 = dy1 * 24 + dx0, P3 = dy1 * 24 + dx1;
        const bool oot = (y0 < ty) | (y1 > ty + 9) | (x0 < tx) | (x1 > tx + 23);

        // 8 ds_read_b128: 4 corners x 2 channel-chunks (q = qc, qc+4), swizzled
        uint4 Q0a = *(const uint4*)&tile[(P0 << 5) + (((qc    ) ^ (P0 & 7)) << 2)];
        uint4 Q0b = *(const uint4*)&tile[(P0 << 5) + (((qc + 4) ^ (P0 & 7)) << 2)];
        uint4 Q1a = *(const uint4*)&tile[(P1 << 5) + (((qc    ) ^ (P1 & 7)) << 2)];
        uint4 Q1b = *(const uint4*)&tile[(P1 << 5) + (((qc + 4) ^ (P1 & 7)) << 2)];
        uint4 Q2a = *(const uint4*)&tile[(P2 << 5) + (((qc    ) ^ (P2 & 7)) << 2)];
        uint4 Q2b = *(const uint4*)&tile[(P2 << 5) + (((qc + 4) ^ (P2 & 7)) << 2)];
        uint4 Q3a = *(const uint4*)&tile[(P3 << 5) + (((qc    ) ^ (P3 & 7)) << 2)];
        uint4 Q3b = *(const uint4*)&tile[(P3 << 5) + (((qc + 4) ^ (P3 & 7)) << 2)];
        if (oot) {  // rare (~0.3% of lane-kn): exact NCHW gather fallback
            const int O0 = (y0 << 7) + x0, O1 = (y0 << 7) + x1;
            const int O2 = (y1 << 7) + x0, O3 = (y1 << 7) + x1;
            const float* p;
            p = xN + O0 + cb * HW;
            Q0a = make_uint4(pk2(p[0], p[HW]), pk2(p[2 * HW], p[3 * HW]),
                             pk2(p[4 * HW], p[5 * HW]), pk2(p[6 * HW], p[7 * HW]));
            p += 32 * HW;
            Q0b = make_uint4(pk2(p[0], p[HW]), pk2(p[2 * HW], p[3 * HW]),
                             pk2(p[4 * HW], p[5 * HW]), pk2(p[6 * HW], p[7 * HW]));
            p = xN + O1 + cb * HW;
            Q1a = make_uint4(pk2(p[0], p[HW]), pk2(p[2 * HW], p[3 * HW]),
                             pk2(p[4 * HW], p[5 * HW]), pk2(p[6 * HW], p[7 * HW]));
            p += 32 * HW;
            Q1b = make_uint4(pk2(p[0], p[HW]), pk2(p[2 * HW], p[3 * HW]),
                             pk2(p[4 * HW], p[5 * HW]), pk2(p[6 * HW], p[7 * HW]));
            p = xN + O2 + cb * HW;
            Q2a = make_uint4(pk2(p[0], p[HW]), pk2(p[2 * HW], p[3 * HW]),
                             pk2(p[4 * HW], p[5 * HW]), pk2(p[6 * HW], p[7 * HW]));
            p += 32 * HW;
            Q2b = make_uint4(pk2(p[0], p[HW]), pk2(p[2 * HW], p[3 * HW]),
                             pk2(p[4 * HW], p[5 * HW]), pk2(p[6 * HW], p[7 * HW]));
            p = xN + O3 + cb * HW;
            Q3a = make_uint4(pk2(p[0], p[HW]), pk2(p[2 * HW], p[3 * HW]),
                             pk2(p[4 * HW], p[5 * HW]), pk2(p[6 * HW], p[7 * HW]));
            p += 32 * HW;
            Q3b = make_uint4(pk2(p[0], p[HW]), pk2(p[2 * HW], p[3 * HW]),
                             pk2(p[4 * HW], p[5 * HW]), pk2(p[6 * HW], p[7 * HW]));
        }

#pragma unroll
        for (int cc = 0; cc < 2; cc++) {
            const u32* c0 = (const u32*)(cc ? &Q0b : &Q0a);
            const u32* c1 = (const u32*)(cc ? &Q1b : &Q1a);
            const u32* c2 = (const u32*)(cc ? &Q2b : &Q2a);
            const u32* c3 = (const u32*)(cc ? &Q3b : &Q3a);
            union { u32 u[4]; bf16x8 v; } B;
#pragma unroll
            for (int k = 0; k < 4; k++) {
                float2 s = up2v(c0[k]);
                s.x *= W0; s.y *= W0;
                float2 t1 = up2v(c1[k]);
                s.x = fmaf(t1.x, W1, s.x); s.y = fmaf(t1.y, W1, s.y);
                float2 t2 = up2v(c2[k]);
                s.x = fmaf(t2.x, W2, s.x); s.y = fmaf(t2.y, W2, s.y);
                float2 t3 = up2v(c3[k]);
                s.x = fmaf(t3.x, W3, s.x); s.y = fmaf(t3.y, W3, s.y);
                B.u[k] = pkrn(s);
            }
#pragma unroll
            for (int s4 = 0; s4 < 4; s4++) {
                bf16x8 A = wfv[((((kn << 1) + cc) << 2) + s4) * 64 + l];
                acc[s4] = __builtin_amdgcn_mfma_f32_16x16x32_bf16(A, B.v, acc[s4], 0, 0, 0);
            }
        }
    }

    // epilogue: D layout col(pixel)=l&15, row(oc-in-strip)=(l>>4)*4+reg.
    // lanes 0..15 -> 16 consecutive ow: each store instr = 4 dense 64B lines.
    const int rq = l >> 4;
    float* op = out + ((size_t)(n * OCH) << 14);
#pragma unroll
    for (int s = 0; s < 4; s++) {
        const int ocb = (s << 4) + (rq << 2);
#pragma unroll
        for (int g = 0; g < 4; g++) {
            op[((ocb + g) << 14) + rr] = acc[s][g];
        }
    }
}

// ---- fallback (ws too small): round-1 style direct kernel
__global__ __launch_bounds__(256) void dcn_fallback_kernel(
    const float* __restrict__ x, const float* __restrict__ off,
    const float* __restrict__ w, float* __restrict__ out) {
    int p = blockIdx.x * blockDim.x + threadIdx.x;
    int n = p / HW, r = p % HW, oh = r / WW, ow = r % WW;
    float acc[OCH];
#pragma unroll
    for (int i = 0; i < OCH; i++) acc[i] = 0.f;
    const float* xn = x + n * (CI * HW);
    const float* offn = off + n * (2 * KNN * HW);
    for (int kn = 0; kn < KNN; kn++) {
        float iy = (float)oh + offn[(2 * kn) * HW + r];
        float ix = (float)ow + offn[(2 * kn + 1) * HW + r];
        float y0f = floorf(iy), x0f = floorf(ix);
        float wy1 = iy - y0f, wy0 = 1.f - wy1, wx1 = ix - x0f, wx0 = 1.f - wx1;
        float my0 = (y0f >= 0.f && y0f <= 127.f) ? 1.f : 0.f;
        float my1 = (y0f >= -1.f && y0f <= 126.f) ? 1.f : 0.f;
        float mx0 = (x0f >= 0.f && x0f <= 127.f) ? 1.f : 0.f;
        float mx1 = (x0f >= -1.f && x0f <= 126.f) ? 1.f : 0.f;
        float w00 = wy0 * wx0 * my0 * mx0, w01 = wy0 * wx1 * my0 * mx1;
        float w10 = wy1 * wx0 * my1 * mx0, w11 = wy1 * wx1 * my1 * mx1;
        int y0 = min(max((int)y0f, 0), 127), y1 = min(max((int)y0f + 1, 0), 127);
        int x0 = min(max((int)x0f, 0), 127), x1 = min(max((int)x0f + 1, 0), 127);
        int o00 = y0 * WW + x0, o01 = y0 * WW + x1, o10 = y1 * WW + x0, o11 = y1 * WW + x1;
        for (int c = 0; c < CI; c++) {
            const float* xc = xn + c * HW;
            float s = xc[o00] * w00 + xc[o01] * w01 + xc[o10] * w10 + xc[o11] * w11;
#pragma unroll
            for (int oc = 0; oc < OCH; oc++) acc[oc] += w[(oc * CI + c) * KNN + kn] * s;
        }
    }
    float* outp = out + n * (OCH * HW) + r;
#pragma unroll
    for (int oc = 0; oc < OCH; oc++) outp[oc * HW] = acc[oc];
}

extern "C" void kernel_launch(void* const* d_in, const int* in_sizes, int n_in,
                              void* d_out, int out_size, void* d_ws, size_t ws_size,
                              hipStream_t stream) {
    const float* x = (const float*)d_in[0];
    const float* off = (const float*)d_in[1];
    const float* w = (const float*)d_in[2];
    float* out = (float*)d_out;

    const size_t wf_elems = (size_t)KNN * 2 * 4 * 64 * 8;     // 36,864 u16
    const size_t need = wf_elems * sizeof(u16);               // ~73.7 KB

    if (ws_size >= need) {
        u16* wfr = (u16*)d_ws;
        const int wf_blocks = (int)((wf_elems + 255) / 256);  // 144
        wf_prep_kernel<<<wf_blocks, 256, 0, stream>>>(w, wfr);
        dcn_main_kernel<<<NB * 256, 256, 0, stream>>>(x, off, wfr, out);
    } else {
        dcn_fallback_kernel<<<(NB * HW) / 256, 256, 0, stream>>>(x, off, w, out);
    }
}